// Round 13
// baseline (9627.119 us; speedup 1.0000x reference)
//
#include <hip/hip_runtime.h>
#include <math.h>

#define VOCAB 32000
#define HID   1024
#define BATCH 8
#define SEQ   512
#define GD    (4*HID)       // 4096 gate width
#define ROWS  (BATCH*SEQ)   // 4096
#define SNB   64            // persistent scan blocks (1 per CU, 64 flags)

typedef __attribute__((ext_vector_type(8))) short short8;
typedef __attribute__((ext_vector_type(4))) float f32x4;

__device__ __forceinline__ float hi_f32(float x) {
    return __uint_as_float(__float_as_uint(x) & 0xFFFF0000u);
}
// packed word: hi bf16 bits in high half, lo bf16 bits in low half
__device__ __forceinline__ unsigned pack_pair(float x) {
    unsigned hb = __float_as_uint(x) & 0xFFFF0000u;
    float lo = x - __uint_as_float(hb);
    return hb | (__float_as_uint(lo) >> 16);
}
__device__ __forceinline__ unsigned pack_hi2(float x, float y) {
    return (__float_as_uint(x) >> 16) | (__float_as_uint(y) & 0xFFFF0000u);
}

// async 16B/lane global->LDS (dest = wave-uniform base + lane*16)
__device__ __forceinline__ void gload16(const void* g, void* l) {
    __builtin_amdgcn_global_load_lds(
        (__attribute__((address_space(1))) void*)g,
        (__attribute__((address_space(3))) void*)l, 16, 0, 0);
}

// ---------------------------------------------------------------------------
// 1) Embedding gather, split: emb_hi/lo[row][h] = split(w_out[h][ids[row]])
// ---------------------------------------------------------------------------
__global__ __launch_bounds__(256) void k_gather_split(const int* __restrict__ ids,
                                                      const float* __restrict__ w_out,
                                                      unsigned short* __restrict__ emb_hi,
                                                      unsigned short* __restrict__ emb_lo)
{
    int row = blockIdx.x;            // 0..4095
    int id  = ids[row];
    const float* src = w_out + id;   // column id, stride VOCAB
    for (int h = threadIdx.x; h < HID; h += 256) {
        float v  = src[(size_t)h * VOCAB];
        float lo = v - hi_f32(v);
        emb_hi[(size_t)row*HID + h] = (unsigned short)(__float_as_uint(v)  >> 16);
        emb_lo[(size_t)row*HID + h] = (unsigned short)(__float_as_uint(lo) >> 16);
    }
}

// ---------------------------------------------------------------------------
// 2) Transpose + split: W[K=1024][N] f32 -> hiT/loT[N][1024] bf16 bits
// ---------------------------------------------------------------------------
__global__ __launch_bounds__(256) void k_transsplit(const float* __restrict__ W,
                                                    unsigned short* __restrict__ hiT,
                                                    unsigned short* __restrict__ loT,
                                                    int N)
{
    __shared__ float tile[32][33];
    int tx = threadIdx.x, ty = threadIdx.y;
    int x = blockIdx.x*32 + tx;      // N
    int y = blockIdx.y*32 + ty;      // K
    #pragma unroll
    for (int i = 0; i < 32; i += 8)
        tile[ty + i][tx] = W[(size_t)(y + i)*N + x];
    __syncthreads();
    int n = blockIdx.x*32 + ty;
    int k = blockIdx.y*32 + tx;
    #pragma unroll
    for (int i = 0; i < 32; i += 8) {
        float v  = tile[tx][ty + i];
        float lo = v - hi_f32(v);
        hiT[(size_t)(n + i)*HID + k] = (unsigned short)(__float_as_uint(v)  >> 16);
        loT[(size_t)(n + i)*HID + k] = (unsigned short)(__float_as_uint(lo) >> 16);
    }
}

// ---------------------------------------------------------------------------
// 2c) Split fp32 -> hi bf16, lo bf16 arrays (grid-stride, float4)
// ---------------------------------------------------------------------------
__global__ __launch_bounds__(256) void k_split_f32(const float* __restrict__ src,
                                                   unsigned short* __restrict__ hi,
                                                   unsigned short* __restrict__ lo,
                                                   long n4)
{
    long i0 = (long)blockIdx.x * 256 + threadIdx.x;
    long stride = (long)gridDim.x * 256;
    for (long i = i0; i < n4; i += stride) {
        float4 v = ((const float4*)src)[i];
        unsigned h0 = __float_as_uint(v.x) >> 16, h1 = __float_as_uint(v.y) >> 16;
        unsigned h2 = __float_as_uint(v.z) >> 16, h3 = __float_as_uint(v.w) >> 16;
        unsigned l0 = __float_as_uint(v.x - hi_f32(v.x)) >> 16;
        unsigned l1 = __float_as_uint(v.y - hi_f32(v.y)) >> 16;
        unsigned l2 = __float_as_uint(v.z - hi_f32(v.z)) >> 16;
        unsigned l3 = __float_as_uint(v.w - hi_f32(v.w)) >> 16;
        ((uint2*)hi)[i] = make_uint2(h0 | (h1 << 16), h2 | (h3 << 16));
        ((uint2*)lo)[i] = make_uint2(l0 | (l1 << 16), l2 | (l3 << 16));
    }
}

// ---------------------------------------------------------------------------
// 3) Fast split-bf16 MFMA GEMM, all operands K-major bf16 bits (R8 proven).
// ---------------------------------------------------------------------------
#define GBM 128
#define GBN 128
#define GBK 32

__global__ __launch_bounds__(256) void k_gemm_fast(
    const unsigned short* __restrict__ Ah,  const unsigned short* __restrict__ Al,
    const unsigned short* __restrict__ BhT, const unsigned short* __restrict__ BlT,
    const float* __restrict__ bias, float* __restrict__ C,
    int M, int N, int K)
{
    __shared__ __align__(16) unsigned short lds[4][4096];  // Ah,Al,Bh,Bl: 8KB each

    const int tid  = threadIdx.x;
    const int lane = tid & 63;
    const int wid  = tid >> 6;
    const int wm = wid >> 1, wn = wid & 1;
    const int l15 = lane & 15, l4 = lane >> 4;
    const int brow = blockIdx.y * GBM;
    const int bcol = blockIdx.x * GBN;

    const int lhi  = lane >> 3;              // 0..7
    const int c8   = (lane & 7) ^ lhi;       // (g&7) == lhi for both chunks
    const int koff = (c8 & 3) * 8;           // element offset in k
    const int r0   = 32*wid + 2*lhi + (c8 >> 2);
    const int r1   = r0 + 16;
    const size_t a0 = (size_t)(brow + r0)*K + koff;
    const size_t a1 = (size_t)(brow + r1)*K + koff;
    const size_t b0 = (size_t)(bcol + r0)*K + koff;
    const size_t b1 = (size_t)(bcol + r1)*K + koff;
    char* lbase = (char*)&lds[0][0];
    const int cb0 = wid*2048, cb1 = wid*2048 + 1024;  // wave-uniform chunk bases

    const int ra = wm*64 + l15;
    const int ga = ra >> 1;
    const int abyte = ga*128 + (((((ra & 1) << 2) | l4) ^ (ga & 7)) << 4);
    const int rb = wn*64 + l15;
    const int gb = rb >> 1;
    const int bbyte = gb*128 + (((((rb & 1) << 2) | l4) ^ (gb & 7)) << 4);

    f32x4 acc[4][4] = {};

    for (int k0 = 0; k0 < K; k0 += GBK) {
        gload16(Ah  + a0 + k0, lbase         + cb0);
        gload16(Ah  + a1 + k0, lbase         + cb1);
        gload16(Al  + a0 + k0, lbase + 8192  + cb0);
        gload16(Al  + a1 + k0, lbase + 8192  + cb1);
        gload16(BhT + b0 + k0, lbase + 16384 + cb0);
        gload16(BhT + b1 + k0, lbase + 16384 + cb1);
        gload16(BlT + b0 + k0, lbase + 24576 + cb0);
        gload16(BlT + b1 + k0, lbase + 24576 + cb1);
        __syncthreads();

        short8 ah[4], al[4], bh[4], bl[4];
        #pragma unroll
        for (int m = 0; m < 4; ++m) {
            ah[m] = *(const short8*)(lbase         + abyte + m*1024);
            al[m] = *(const short8*)(lbase + 8192  + abyte + m*1024);
        }
        #pragma unroll
        for (int n = 0; n < 4; ++n) {
            bh[n] = *(const short8*)(lbase + 16384 + bbyte + n*1024);
            bl[n] = *(const short8*)(lbase + 24576 + bbyte + n*1024);
        }
        #pragma unroll
        for (int n = 0; n < 4; ++n)
            #pragma unroll
            for (int m = 0; m < 4; ++m) {
                acc[m][n] = __builtin_amdgcn_mfma_f32_16x16x32_bf16(ah[m], bh[n], acc[m][n], 0, 0, 0);
                acc[m][n] = __builtin_amdgcn_mfma_f32_16x16x32_bf16(ah[m], bl[n], acc[m][n], 0, 0, 0);
                acc[m][n] = __builtin_amdgcn_mfma_f32_16x16x32_bf16(al[m], bh[n], acc[m][n], 0, 0, 0);
            }
        __syncthreads();
    }

    #pragma unroll
    for (int n = 0; n < 4; ++n) {
        int col = bcol + wn*64 + n*16 + l15;
        float bv = bias[col];
        #pragma unroll
        for (int m = 0; m < 4; ++m) {
            int rbs = brow + wm*64 + m*16 + l4*4;
            #pragma unroll
            for (int r = 0; r < 4; ++r)
                C[(size_t)(rbs + r)*N + col] = acc[m][n][r] + bv;
        }
    }
}

// ---------------------------------------------------------------------------
// 3b) Fallback GEMM (in-kernel conversion, fp32 inputs) — Round-4 proven.
// ---------------------------------------------------------------------------
__global__ __launch_bounds__(256) void k_gemm_mfma(const float* __restrict__ A,
                                                   const float* __restrict__ B,
                                                   const float* __restrict__ bias,
                                                   float* __restrict__ C,
                                                   int M, int N, int K)
{
    __shared__ unsigned short As_hi[GBM][40];
    __shared__ unsigned short As_lo[GBM][40];
    __shared__ unsigned int   Bs[GBK][130];

    int tid  = threadIdx.x;
    int brow = blockIdx.y * GBM;
    int bcol = blockIdx.x * GBN;

    int lane = tid & 63;
    int wid  = tid >> 6;
    int wm   = wid >> 1;
    int wn   = wid & 1;
    int l15  = lane & 15;
    int l4   = lane >> 4;

    int a_m = tid >> 3;
    int a_c = tid & 7;
    int b_k = tid >> 5;
    int b_n = tid & 31;

    f32x4 acc[4][4] = {};

    for (int k0 = 0; k0 < K; k0 += GBK) {
        #pragma unroll
        for (int p = 0; p < 4; ++p) {
            int r = a_m + p*32;
            float4 v = *(const float4*)(A + (size_t)(brow + r)*K + k0 + a_c*4);
            unsigned h0 = pack_hi2(v.x, v.y);
            unsigned h1 = pack_hi2(v.z, v.w);
            float lx = v.x - hi_f32(v.x);
            float ly = v.y - hi_f32(v.y);
            float lz = v.z - hi_f32(v.z);
            float lw = v.w - hi_f32(v.w);
            unsigned l0 = pack_hi2(lx, ly);
            unsigned l1 = pack_hi2(lz, lw);
            *(uint2*)&As_hi[r][a_c*4] = make_uint2(h0, h1);
            *(uint2*)&As_lo[r][a_c*4] = make_uint2(l0, l1);
        }
        #pragma unroll
        for (int p = 0; p < 4; ++p) {
            int kk = b_k + p*8;
            float4 v = *(const float4*)(B + (size_t)(k0 + kk)*N + bcol + b_n*4);
            unsigned w0 = pack_pair(v.x);
            unsigned w1 = pack_pair(v.y);
            unsigned w2 = pack_pair(v.z);
            unsigned w3 = pack_pair(v.w);
            *(uint2*)&Bs[kk][b_n*4]     = make_uint2(w0, w1);
            *(uint2*)&Bs[kk][b_n*4 + 2] = make_uint2(w2, w3);
        }
        __syncthreads();

        short8 ah[4], al[4];
        #pragma unroll
        for (int m = 0; m < 4; ++m) {
            int r = wm*64 + m*16 + l15;
            ah[m] = *(const short8*)&As_hi[r][l4*8];
            al[m] = *(const short8*)&As_lo[r][l4*8];
        }

        #pragma unroll
        for (int n = 0; n < 4; ++n) {
            int col = wn*64 + n*16 + l15;
            unsigned w[8];
            #pragma unroll
            for (int j = 0; j < 8; ++j)
                w[j] = Bs[l4*8 + j][col];
            union { short8 v; unsigned d[4]; } bh, bl;
            #pragma unroll
            for (int d = 0; d < 4; ++d) {
                bh.d[d] = (w[2*d] >> 16)      | (w[2*d+1] & 0xFFFF0000u);
                bl.d[d] = (w[2*d] & 0xFFFFu)  | (w[2*d+1] << 16);
            }
            #pragma unroll
            for (int m = 0; m < 4; ++m) {
                acc[m][n] = __builtin_amdgcn_mfma_f32_16x16x32_bf16(ah[m], bh.v, acc[m][n], 0, 0, 0);
                acc[m][n] = __builtin_amdgcn_mfma_f32_16x16x32_bf16(ah[m], bl.v, acc[m][n], 0, 0, 0);
                acc[m][n] = __builtin_amdgcn_mfma_f32_16x16x32_bf16(al[m], bh.v, acc[m][n], 0, 0, 0);
            }
        }
        __syncthreads();
    }

    #pragma unroll
    for (int n = 0; n < 4; ++n) {
        int col = bcol + wn*64 + n*16 + l15;
        float bv = bias[col];
        #pragma unroll
        for (int m = 0; m < 4; ++m) {
            int rb = brow + wm*64 + m*16 + l4*4;
            #pragma unroll
            for (int r = 0; r < 4; ++r)
                C[(size_t)(rb + r)*N + col] = acc[m][n][r] + bv;
        }
    }
}

// ---------------------------------------------------------------------------
// 4) Persistent MFMA LSTM scan — ONE launch for all 512 steps.
//    64 blocks x 256 thr (1 block/CU, co-resident by capacity). Block owns
//    16 hidden cols; wave = gate (full K per wave -> no cross-wave combine).
//    h crosses blocks as packed (hi|lo) u32 via agent-scope relaxed atomics
//    (write/read-through the coherence point; NO fences -> W/xg stay L2-hot).
//    Barrier: flags[64] (flag[b] = steps completed by b), plain atomic
//    stores (no RMW), 64-lane parallel poll. Wait-at-top / flag-at-end:
//    a block entering step t has seen all blocks complete t-1 -> ping-pong
//    hbuf[2] is race-free. Ordering: __syncthreads drains vmcnt(0) (h-stores
//    acked at coherence point) BEFORE tid0 issues the flag store.
//    c-state lives in tail-thread registers for the whole scan.
// ---------------------------------------------------------------------------
__global__ __launch_bounds__(256) void k_lstm_scan(
    const float* __restrict__ xg,
    const unsigned short* __restrict__ WhT_hi,   // [4096][1024] bf16 bits
    const unsigned short* __restrict__ WhT_lo,
    unsigned int* __restrict__ hbuf,             // [2][8][1024] packed hi|lo
    unsigned int* __restrict__ flags,            // [SNB], zeroed per call
    float* __restrict__ hs)
{
    __shared__ unsigned int h_lds[8][1028];      // padded: bank=(4*row+k)%32
    __shared__ float g_sm[4][16][16];            // [gate][col][row=batch]

    const int tid  = threadIdx.x;
    const int lane = tid & 63;
    const int w    = tid >> 6;        // wave = gate 0..3
    const int l15  = lane & 15;
    const int l4   = lane >> 4;
    const int j0   = blockIdx.x * 16; // 16 hidden cols per block

    // B operand: lane l15 owns W^T column (gate w, hidden col j0+l15)
    const unsigned short* wh = WhT_hi + (size_t)(w*HID + j0 + l15)*HID + l4*8;
    const unsigned short* wl = WhT_lo + (size_t)(w*HID + j0 + l15)*HID + l4*8;

    const int tb = tid & 7;           // tail: batch
    const int tj = tid >> 3;          // tail: local col (valid for tid<128)
    float creg = 0.0f;                // c-state register (tail threads)

    for (int t = 0; t < SEQ; ++t) {
        // prefetch tail xg operands (normal cached loads; consumed post-barrier)
        float xv0 = 0, xv1 = 0, xv2 = 0, xv3 = 0;
        if (tid < 128) {
            size_t xb = ((size_t)tb*SEQ + t)*GD + j0 + tj;
            xv0 = xg[xb];
            xv1 = xg[xb + HID];
            xv2 = xg[xb + 2*HID];
            xv3 = xg[xb + 3*HID];
        }

        if (t > 0) {
            // ---- grid barrier: wait until all blocks completed step t-1 ----
            if (w == 0) {
                while (__hip_atomic_load(&flags[lane], __ATOMIC_RELAXED,
                                         __HIP_MEMORY_SCOPE_AGENT) < (unsigned)t)
                    __builtin_amdgcn_s_sleep(1);
            }
            __syncthreads();

            // ---- stage h(t-1) (packed) into LDS via agent-scope loads ----
            unsigned int* hp = hbuf + ((t - 1) & 1) * (8 * 1024);
            #pragma unroll
            for (int i = 0; i < 32; ++i) {
                int idx = i * 256 + tid;
                h_lds[idx >> 10][idx & 1023] =
                    __hip_atomic_load(hp + idx, __ATOMIC_RELAXED,
                                      __HIP_MEMORY_SCOPE_AGENT);
            }
            __syncthreads();

            // ---- matvec: 32 K-steps x 3 split-bf16 MFMA, 2 acc streams ----
            const unsigned int* hrow = &h_lds[l15 & 7][0];  // lanes 8-15 broadcast
            f32x4 acc0 = {}, acc1 = {};
            #pragma unroll
            for (int ks = 0; ks < 32; ks += 2) {
                uint4 p0a = *(const uint4*)(hrow + ks*32 + l4*8);
                uint4 p0b = *(const uint4*)(hrow + ks*32 + l4*8 + 4);
                uint4 p1a = *(const uint4*)(hrow + (ks+1)*32 + l4*8);
                uint4 p1b = *(const uint4*)(hrow + (ks+1)*32 + l4*8 + 4);
                union { short8 v; unsigned d[4]; } ah0, al0, ah1, al1;
                unsigned q0[8] = {p0a.x,p0a.y,p0a.z,p0a.w,p0b.x,p0b.y,p0b.z,p0b.w};
                unsigned q1[8] = {p1a.x,p1a.y,p1a.z,p1a.w,p1b.x,p1b.y,p1b.z,p1b.w};
                #pragma unroll
                for (int d = 0; d < 4; ++d) {
                    ah0.d[d] = (q0[2*d] >> 16)     | (q0[2*d+1] & 0xFFFF0000u);
                    al0.d[d] = (q0[2*d] & 0xFFFFu) | (q0[2*d+1] << 16);
                    ah1.d[d] = (q1[2*d] >> 16)     | (q1[2*d+1] & 0xFFFF0000u);
                    al1.d[d] = (q1[2*d] & 0xFFFFu) | (q1[2*d+1] << 16);
                }
                short8 bh0 = *(const short8*)(wh + ks*32);
                short8 bl0 = *(const short8*)(wl + ks*32);
                short8 bh1 = *(const short8*)(wh + (ks+1)*32);
                short8 bl1 = *(const short8*)(wl + (ks+1)*32);
                acc0 = __builtin_amdgcn_mfma_f32_16x16x32_bf16(ah0.v, bh0, acc0, 0, 0, 0);
                acc1 = __builtin_amdgcn_mfma_f32_16x16x32_bf16(ah1.v, bh1, acc1, 0, 0, 0);
                acc0 = __builtin_amdgcn_mfma_f32_16x16x32_bf16(ah0.v, bl0, acc0, 0, 0, 0);
                acc1 = __builtin_amdgcn_mfma_f32_16x16x32_bf16(ah1.v, bl1, acc1, 0, 0, 0);
                acc0 = __builtin_amdgcn_mfma_f32_16x16x32_bf16(al0.v, bh0, acc0, 0, 0, 0);
                acc1 = __builtin_amdgcn_mfma_f32_16x16x32_bf16(al1.v, bh1, acc1, 0, 0, 0);
            }
            f32x4 acc = acc0 + acc1;
            // C/D layout: col = l15 (local col), row = l4*4+r (batch; 8-15 pad)
            *(f32x4*)&g_sm[w][l15][l4*4] = acc;
        }
        __syncthreads();

        // ---- tail: activations + state update (128 threads) ----
        if (tid < 128) {
            float s0 = 0, s1 = 0, s2 = 0, s3 = 0;
            if (t > 0) {
                s0 = g_sm[0][tj][tb];
                s1 = g_sm[1][tj][tb];
                s2 = g_sm[2][tj][tb];
                s3 = g_sm[3][tj][tb];
            }
            float iv = s0 + xv0;
            float fv = s1 + xv1;
            float gv = s2 + xv2;
            float ov = s3 + xv3;
            iv = 1.0f / (1.0f + expf(-iv));
            fv = 1.0f / (1.0f + expf(-fv));
            gv = tanhf(gv);
            ov = 1.0f / (1.0f + expf(-ov));
            float cn = fv*creg + iv*gv;
            creg = cn;
            float hn = ov * tanhf(cn);
            int jc = j0 + tj;
            hs[((size_t)tb*SEQ + t)*HID + jc] = hn;
            unsigned hb2 = __float_as_uint(hn) & 0xFFFF0000u;
            unsigned pk  = hb2 |
                (__float_as_uint(hn - __uint_as_float(hb2)) >> 16);
            __hip_atomic_store(hbuf + (t & 1)*(8*1024) + (size_t)tb*1024 + jc,
                               pk, __ATOMIC_RELAXED, __HIP_MEMORY_SCOPE_AGENT);
        }
        __syncthreads();   // drains vmcnt(0): h-stores acked before flag store

        if (t < SEQ - 1 && tid == 0)
            __hip_atomic_store(&flags[blockIdx.x], (unsigned)(t + 1),
                               __ATOMIC_RELAXED, __HIP_MEMORY_SCOPE_AGENT);
    }
}

// ---------------------------------------------------------------------------
// Launch
// ---------------------------------------------------------------------------
extern "C" void kernel_launch(void* const* d_in, const int* in_sizes, int n_in,
                              void* d_out, int out_size, void* d_ws, size_t ws_size,
                              hipStream_t stream)
{
    const int*   ids    = (const int*)  d_in[0];
    const float* w_out  = (const float*)d_in[1];
    const float* b_out  = (const float*)d_in[2];
    const float* W_ih   = (const float*)d_in[3];
    const float* W_hh   = (const float*)d_in[4];
    const float* b_lstm = (const float*)d_in[5];
    float* out = (float*)d_out;

    // d_out scratch (524 MB): every region dead before the final GEMM writes C.
    char* ob = (char*)d_out;
    unsigned short* emb_hi  = (unsigned short*)(ob);               //  8,388,608 B
    unsigned short* emb_lo  = (unsigned short*)(ob + 8388608);     //  8,388,608 B
    unsigned short* whh_hiT = (unsigned short*)(ob + 16777216);    //  8,388,608 B
    unsigned short* whh_loT = (unsigned short*)(ob + 25165824);    //  8,388,608 B
    float*          xg      = (float*)(ob + 33554432);             // 67,108,864 B
    unsigned int*   hbuf    = (unsigned int*)(ob + 100663296);     //     65,536 B
    unsigned int*   flags   = (unsigned int*)(ob + 100728832);     //        256 B
    unsigned short* wih_hiT = (unsigned short*)(ob + 100732928);   //  8,388,608 B
    unsigned short* wih_loT = (unsigned short*)(ob + 109121536);   //  8,388,608 B
    float*          hs_dout = (float*)(ob + 117510144);            // 16,777,216 B

    // d_ws: fast path needs hs_hi/lo + w_out^T hi/lo = 147,849,216 B.
    char* wb = (char*)d_ws;
    const size_t NEED = 147849216ull;
    const bool big_ws = (ws_size >= NEED);
    unsigned short* hs_hi  = (unsigned short*)(wb);                //  8,388,608 B
    unsigned short* hs_lo  = (unsigned short*)(wb + 8388608);      //  8,388,608 B
    unsigned short* wo_hiT = (unsigned short*)(wb + 16777216);     // 65,536,000 B
    unsigned short* wo_loT = (unsigned short*)(wb + 82313216);     // 65,536,000 B
    float* hs = big_ws ? hs_dout : (float*)wb;

    // 1) embedding gather (split to hi/lo bf16)
    k_gather_split<<<ROWS, 256, 0, stream>>>(ids, w_out, emb_hi, emb_lo);

    // 2) W_hh -> transposed hi/lo bf16 [4096][1024] (scan B-operand)
    k_transsplit<<<dim3(GD/32, HID/32), dim3(32, 8), 0, stream>>>(
        W_hh, whh_hiT, whh_loT, GD);

    // 2b) W_ih -> transposed hi/lo bf16 [4096][1024]
    k_transsplit<<<dim3(GD/32, HID/32), dim3(32, 8), 0, stream>>>(
        W_ih, wih_hiT, wih_loT, GD);

    // 3) x_gates = emb @ W_ih + b_lstm  (K-major fast MFMA GEMM)
    k_gemm_fast<<<dim3(GD/GBN, ROWS/GBM), 256, 0, stream>>>(
        emb_hi, emb_lo, wih_hiT, wih_loT, b_lstm, xg, ROWS, GD, HID);

    // 4) persistent scan: ONE launch (flags zeroed each call)
    hipMemsetAsync((void*)flags, 0, SNB * sizeof(unsigned int), stream);
    k_lstm_scan<<<SNB, 256, 0, stream>>>(
        xg, whh_hiT, whh_loT, hbuf, flags, hs);

    // 5) logits = hs @ w_out + b_out
    if (big_ws) {
        k_transsplit<<<dim3(VOCAB/32, HID/32), dim3(32, 8), 0, stream>>>(
            w_out, wo_hiT, wo_loT, VOCAB);
        k_split_f32<<<1024, 256, 0, stream>>>(hs, hs_hi, hs_lo, (long)ROWS*HID/4);
        k_gemm_fast<<<dim3(VOCAB/GBN, ROWS/GBM), 256, 0, stream>>>(
            hs_hi, hs_lo, wo_hiT, wo_loT, b_out, out, ROWS, VOCAB, HID);
    } else {
        k_gemm_mfma<<<dim3(VOCAB/GBN, ROWS/GBM), 256, 0, stream>>>(
            hs, w_out, b_out, out, ROWS, VOCAB, HID);
    }
}